// Round 1
// baseline (737.998 us; speedup 1.0000x reference)
//
#include <hip/hip_runtime.h>

// B=4, T=2048, C=1024, V=50257
// loss = mean_i [ log(sum_v exp(x_i.W_v + b_v)) - (x_i.W_{y_i} + b_{y_i}) ]
// R4: no-LDS fp8 GEMM with 128x64 wave tile (4x2 MFMA 32x32x64) -> 85 FLOP/B
// fragment traffic, MFMA-bound. Coalesced pack kernels. Output transposed
// (rows=vocab): softmax sum = per-lane adds + one shfl.
// R5: XCD-aware block swizzle. Each XCD owns 8 mblks (1MB of pX, L2-resident)
// and walks all vblks 8-mblks-at-a-time: concurrent working set/XCD ~3MB < 4MiB
// L2, A-panels get 8x L2 reuse. Goal: loads at L2 latency so 2 waves/SIMD can
// hide them under the 8x64cyc MFMA burst per K-block.

#define M_TOT 8192
#define K_TOT 1024
#define V_TOT 50257
#define NVB   197                // vocab blocks of 256
#define NPAD  (NVB * 256)        // 50432
#define PSTRIDE (NVB * 2)        // 394 partials per batch row
#define KB    (K_TOT / 64)       // 16 K-blocks of 64
#define GSTRIDE ((long)KB * 64 * 32)   // bytes per packed 32-row group

typedef __attribute__((ext_vector_type(8)))  int   int8v;
typedef __attribute__((ext_vector_type(16))) float floatx16;

__device__ __forceinline__ int f4_to_fp8x4(float4 v) {
  int r = __builtin_amdgcn_cvt_pk_fp8_f32(v.x, v.y, 0, false);
  r = __builtin_amdgcn_cvt_pk_fp8_f32(v.z, v.w, r, true);
  return r;
}

// Packed layout (verified R3): for 32-row group g, K-block kb, MFMA lane
// l = h*32 + r (h = k-half, r = row-in-group), byte c in 0..31:
//   p[((g*KB+kb)*64 + l)*32 + c] = fp8(src[g*32 + r][kb*64 + h*32 + c])
// Block = one (kb, g): 32 rows x 64 cols. Thread i: row r=i>>3, seg=i&3..7 —
// reads 8 contiguous floats (2x float4, coalesced 128B/8-thread-row),
// writes one 8B chunk piece (locally coalesced).
__global__ __launch_bounds__(256) void pack_kernel(
    const float* __restrict__ src, char* __restrict__ dst, int nrows) {
  const int kb = blockIdx.x, g = blockIdx.y;
  const int i = threadIdx.x;
  const int r = i >> 3, seg = i & 7;
  const int srow = g * 32 + r;
  int lo = 0, hi = 0;
  if (srow < nrows) {
    const float4* s = (const float4*)(src + (long)srow * K_TOT + kb * 64 + seg * 8);
    lo = f4_to_fp8x4(s[0]);
    hi = f4_to_fp8x4(s[1]);
  }
  const int h = seg >> 2;
  char* d = dst + (((long)(g * KB + kb) * 64 + h * 32 + r) * 32 + (seg & 3) * 8);
  *(int2*)d = make_int2(lo, hi);
}

// Block tile: 256 vocab x 128 batch. 4 waves 2x2 (wv, wb); each wave
// 128 vocab x 64 batch via 4x2 mfma_scale_f32_32x32x64_f8f6f4 (unit scales =
// plain fp8). Fragments streamed from packed global: per (group, kb) a wave
// reads one contiguous 2KB span (perfectly coalesced, L1/L2-served).
// Block swizzle: linear id (x-fastest dispatch) -> xcd = lin&7 (HW round-robin
// heuristic). Per XCD: mblk in [xcd*8, xcd*8+8), vblk sweeps 0..196 with the
// 8 mblks cycling fastest. Bijective since 12608 % 8 == 0.
__global__ __launch_bounds__(256, 2) void gemm_lse_kernel(
    const char* __restrict__ pW, const char* __restrict__ pX,
    const float* __restrict__ bias, float* __restrict__ psum) {
  const int tid  = threadIdx.x;
  const int wave = tid >> 6;
  const int lane = tid & 63;
  const int wv   = wave >> 1;            // vocab half (128 rows)
  const int wb   = wave & 1;             // batch half (64 cols)

  const int lin  = blockIdx.y * 64 + blockIdx.x;   // 0..12607, x fastest
  const int xcd  = lin & 7;
  const int idx  = lin >> 3;                       // 0..1575 within XCD
  const int mblk = (xcd << 3) | (idx & 7);         // 8 mblks per XCD
  const int vblk = idx >> 3;                       // 0..196

  const char* pa[4];
  const char* pb[2];
#pragma unroll
  for (int tv = 0; tv < 4; ++tv)
    pa[tv] = pW + (long)(vblk * 8 + wv * 4 + tv) * GSTRIDE + (long)lane * 32;
#pragma unroll
  for (int tn = 0; tn < 2; ++tn)
    pb[tn] = pX + (long)(mblk * 4 + wb * 2 + tn) * GSTRIDE + (long)lane * 32;

  floatx16 acc[4][2] = {};
#pragma unroll 2
  for (int kb = 0; kb < KB; ++kb) {
    const int off = kb * 2048;
    int8v a[4], b[2];
#pragma unroll
    for (int tn = 0; tn < 2; ++tn) b[tn] = *(const int8v*)(pb[tn] + off);
#pragma unroll
    for (int tv = 0; tv < 4; ++tv) a[tv] = *(const int8v*)(pa[tv] + off);
#pragma unroll
    for (int tv = 0; tv < 4; ++tv)
#pragma unroll
      for (int tn = 0; tn < 2; ++tn)
        acc[tv][tn] = __builtin_amdgcn_mfma_scale_f32_32x32x64_f8f6f4(
            a[tv], b[tn], acc[tv][tn], 0, 0, 0, 0x7F7F7F7F, 0, 0x7F7F7F7F);
  }

  // Epilogue. C layout (verified R2/R3): col(batch) = l32,
  // row(vocab within 32-group) = (reg&3) + 8*(reg>>2) + 4*half.
  const int half = lane >> 5, l32 = lane & 31;
  const int vbase = vblk * 256 + wv * 128 + 4 * half;
  float s0 = 0.0f, s1 = 0.0f;
#pragma unroll
  for (int tv = 0; tv < 4; ++tv) {
#pragma unroll
    for (int reg = 0; reg < 16; ++reg) {
      int v = vbase + tv * 32 + (reg & 3) + 8 * (reg >> 2);
      float bv = (v < V_TOT) ? bias[v] : -1e30f;   // exp -> 0 for pad rows
      s0 += __expf(acc[tv][0][reg] + bv);
      s1 += __expf(acc[tv][1][reg] + bv);
    }
  }
  s0 += __shfl_xor(s0, 32, 64);
  s1 += __shfl_xor(s1, 32, 64);
  if (half == 0) {
    int m = mblk * 128 + wb * 64 + l32;
    long base = (long)m * PSTRIDE + vblk * 2 + wv;
    psum[base] = s0;                                // tn = 0
    psum[base + (long)32 * PSTRIDE] = s1;           // tn = 1 (m + 32)
  }
}

// One wave per batch row: sum 394 partials -> log; exact fp32 label logit.
__global__ __launch_bounds__(256) void finalize_kernel(
    const float* __restrict__ psum, const float* __restrict__ x,
    const float* __restrict__ W, const float* __restrict__ b,
    const int* __restrict__ y, float* __restrict__ loss) {
  const int wave = threadIdx.x >> 6;
  const int lane = threadIdx.x & 63;
  const int r = blockIdx.x * 4 + wave;

  const float* ps = psum + (long)r * PSTRIDE;
  float s = 0.0f;
  for (int j = lane; j < PSTRIDE; j += 64) s += ps[j];
#pragma unroll
  for (int o = 1; o < 64; o <<= 1) s += __shfl_xor(s, o, 64);

  int label = y[r];
  const float4* xr = (const float4*)(x + (long)r * K_TOT);
  const float4* wr = (const float4*)(W + (long)label * K_TOT);
  float d = 0.0f;
  for (int j = lane; j < K_TOT / 4; j += 64) {
    float4 a = xr[j], w = wr[j];
    d += a.x * w.x + a.y * w.y + a.z * w.z + a.w * w.w;
  }
#pragma unroll
  for (int o = 1; o < 64; o <<= 1) d += __shfl_xor(d, o, 64);

  if (lane == 0) loss[r] = logf(s) - d - b[label];
}

// Single block: deterministic mean of 8192 per-row losses.
__global__ __launch_bounds__(256) void reduce_kernel(
    const float* __restrict__ loss, float* __restrict__ out) {
  const int tid = threadIdx.x;
  float s = 0.0f;
  for (int j = tid; j < M_TOT; j += 256) s += loss[j];
#pragma unroll
  for (int o = 1; o < 64; o <<= 1) s += __shfl_xor(s, o, 64);
  __shared__ float wsum[4];
  if ((tid & 63) == 0) wsum[tid >> 6] = s;
  __syncthreads();
  if (tid == 0)
    out[0] = (wsum[0] + wsum[1] + wsum[2] + wsum[3]) * (1.0f / (float)M_TOT);
}

extern "C" void kernel_launch(void* const* d_in, const int* in_sizes, int n_in,
                              void* d_out, int out_size, void* d_ws, size_t ws_size,
                              hipStream_t stream) {
  (void)in_sizes; (void)n_in; (void)out_size; (void)ws_size;
  const float* x = (const float*)d_in[0];
  const int*   y = (const int*)d_in[1];
  const float* W = (const float*)d_in[2];
  const float* b = (const float*)d_in[3];
  float* out = (float*)d_out;

  char* ws = (char*)d_ws;
  const size_t PX_BYTES = (size_t)M_TOT * K_TOT;            // 8.4 MB
  const size_t PW_BYTES = (size_t)NPAD * K_TOT;             // 51.6 MB
  const size_t PS_BYTES = (size_t)M_TOT * PSTRIDE * 4;      // 12.9 MB
  char*  pX   = ws;
  char*  pW   = ws + PX_BYTES;
  float* psum = (float*)(ws + PX_BYTES + PW_BYTES);
  float* loss = (float*)(ws + PX_BYTES + PW_BYTES + PS_BYTES);

  pack_kernel<<<dim3(KB, M_TOT / 32), 256, 0, stream>>>(x, pX, M_TOT);
  pack_kernel<<<dim3(KB, NPAD / 32), 256, 0, stream>>>(W, pW, V_TOT);
  gemm_lse_kernel<<<dim3(M_TOT / 128, NVB), 256, 0, stream>>>(pW, pX, b, psum);
  finalize_kernel<<<M_TOT / 4, 256, 0, stream>>>(psum, x, W, b, y, loss);
  reduce_kernel<<<1, 256, 0, stream>>>(loss, out);
}